// Round 14
// baseline (32.382 us; speedup 1.0000x reference)
//
#include <hip/hip_runtime.h>

#define TLEN 4096
#define NT 256
#define SEG 1024
#define OFF 24              // left halo capacity (need 21); 96 B, 16B-aligned
#define BUFW 1088           // 24 + 1024 + 28 = 1076, padded to 1088
#define NSEGS 4

typedef float f32x4 __attribute__((ext_vector_type(4)));
typedef float f32x2 __attribute__((ext_vector_type(2)));

__device__ __forceinline__ f32x4 ldv4(const float* p) {
    return *reinterpret_cast<const f32x4*>(p);
}

// LDS-only barrier: drain LDS ops, do NOT drain vmcnt (global loads/stores stay in flight)
__device__ __forceinline__ void bar_lds() {
    asm volatile("s_waitcnt lgkmcnt(0)" ::: "memory");
    __builtin_amdgcn_s_barrier();
}

// compile-time window element extraction (all n constant after unroll)
#define W16(n) ((n) < 4 ? qa[(n)] : (n) < 8 ? qb[(n)-4] : (n) < 12 ? qc[(n)-8] : qd[(n)-12])
#define W20(n) ((n) < 4 ? qa[(n)] : (n) < 8 ? qb[(n)-4] : (n) < 12 ? qc[(n)-8] : (n) < 16 ? qd[(n)-12] : qe[(n)-16])
#define W32(n) ((n) < 4 ? qa[(n)] : (n) < 8 ? qb[(n)-4] : (n) < 12 ? qc[(n)-8] : (n) < 16 ? qd[(n)-12] : \
                (n) < 20 ? qe[(n)-16] : (n) < 24 ? qf[(n)-20] : (n) < 28 ? qg[(n)-24] : qh[(n)-28])

__global__ __launch_bounds__(NT) void swt_db4_l3_kernel(
    const float* __restrict__ x,
    const float* __restrict__ lo_g,
    const float* __restrict__ hi_g,
    float* __restrict__ out)
{
    __shared__ float bufX[BUFW];      // x, later A2
    __shared__ float bufY[BUFW];      // A1
    __shared__ float pl[4][SEG];      // channel-planar staging (NOT aliased)

    const int row = blockIdx.x;
    const int tid = threadIdx.x;

    f32x2 c[8];
#pragma unroll
    for (int j = 0; j < 8; ++j) { c[j].x = lo_g[j]; c[j].y = hi_g[j]; }

    const float* xr = x + (size_t)row * TLEN;
    f32x4* outb = reinterpret_cast<f32x4*>(out + (size_t)row * TLEN * 4);

    // fixed halo slot: u in [-21,-1] (tid<21) or [1024,1052) (21<=tid<49)
    const int hu = (tid < 21) ? (tid - 21) : (SEG + tid - 21);

    // ---- prologue prefetch: segment 0 ----
    f32x4 xpre = ldv4(xr + 4 * tid);
    float xh = (tid < 49) ? xr[hu & (TLEN - 1)] : 0.f;

    for (int s = 0; s < NSEGS; ++s) {
        // ---- stage current segment into bufX ----
        *reinterpret_cast<f32x4*>(&bufX[OFF + 4 * tid]) = xpre;
        if (tid < 49) bufX[OFF + hu] = xh;
        bar_lds();

        // ---- issue next segment's loads; waited only at next-iteration use ----
        f32x4 xnext;
        float xhn = 0.f;
        if (s + 1 < NSEGS) {
            xnext = ldv4(xr + (s + 1) * SEG + 4 * tid);
            if (tid < 49) xhn = xr[((s + 1) * SEG + hu) & (TLEN - 1)];
        }

        float d1[4], d2[4], a3[4], d3[4];

        // ---- Level 1 (dil=1): window [4t-4, 4t+12), tap(i,j) = W16(i+8-j) ----
        {
            const float* b = &bufX[OFF + 4 * tid - 4];
            f32x4 qa = ldv4(b), qb = ldv4(b + 4), qc = ldv4(b + 8), qd = ldv4(b + 12);
            f32x2 acc[4];
#pragma unroll
            for (int i = 0; i < 4; ++i) { acc[i].x = 0.f; acc[i].y = 0.f; }
#pragma unroll
            for (int j = 0; j < 8; ++j)
#pragma unroll
                for (int i = 0; i < 4; ++i) {
                    float v = W16(i + 8 - j);
                    f32x2 vv; vv.x = v; vv.y = v;
                    acc[i] = __builtin_elementwise_fma(c[j], vv, acc[i]);
                }
            f32x4 av; av.x = acc[0].x; av.y = acc[1].x; av.z = acc[2].x; av.w = acc[3].x;
            *reinterpret_cast<f32x4*>(&bufY[OFF + 4 * tid]) = av;
#pragma unroll
            for (int i = 0; i < 4; ++i) d1[i] = acc[i].y;
        }
        if (tid < 42) {   // edge A1 (A only): u in [-18,-1] and [1024,1048)
            int u = (tid < 18) ? (tid - 18) : (SEG + tid - 18);
            const float* sp = &bufX[OFF + u];
            float a = 0.f;
#pragma unroll
            for (int j = 0; j < 8; ++j) a = fmaf(c[j].x, sp[4 - j], a);
            bufY[OFF + u] = a;
        }
        bar_lds();

        // ---- store PREVIOUS segment (pl written last iteration, barrier-separated);
        //      drains under L2+L3 compute ----
        if (s > 0) {
            f32x4* outr = outb + (s - 1) * SEG;
#pragma unroll
            for (int k = 0; k < 4; ++k) {
                int t = tid + k * NT;
                f32x4 o;
                o.x = pl[0][t]; o.y = pl[1][t]; o.z = pl[2][t]; o.w = pl[3][t];
                outr[t] = o;
            }
        }

        // ---- Level 2 (dil=2): window [4t-8, 4t+12), tap(i,j) = W20(i+16-2j) ----
        {
            const float* b = &bufY[OFF + 4 * tid - 8];
            f32x4 qa = ldv4(b), qb = ldv4(b + 4), qc = ldv4(b + 8), qd = ldv4(b + 12), qe = ldv4(b + 16);
            f32x2 acc[4];
#pragma unroll
            for (int i = 0; i < 4; ++i) { acc[i].x = 0.f; acc[i].y = 0.f; }
#pragma unroll
            for (int j = 0; j < 8; ++j)
#pragma unroll
                for (int i = 0; i < 4; ++i) {
                    float v = W20(i + 16 - 2 * j);
                    f32x2 vv; vv.x = v; vv.y = v;
                    acc[i] = __builtin_elementwise_fma(c[j], vv, acc[i]);
                }
            f32x4 av; av.x = acc[0].x; av.y = acc[1].x; av.z = acc[2].x; av.w = acc[3].x;
            *reinterpret_cast<f32x4*>(&bufX[OFF + 4 * tid]) = av;   // x dead after L1
#pragma unroll
            for (int i = 0; i < 4; ++i) d2[i] = acc[i].y;
        }
        if (tid < 28) {   // edge A2 (A only): u in [-12,-1] and [1024,1040)
            int u = (tid < 12) ? (tid - 12) : (SEG + tid - 12);
            const float* sp = &bufY[OFF + u];
            float a = 0.f;
#pragma unroll
            for (int j = 0; j < 8; ++j) a = fmaf(c[j].x, sp[(4 - j) * 2], a);
            bufX[OFF + u] = a;
        }
        bar_lds();

        // ---- Level 3 (dil=4): window [4t-12, 4t+20), tap(i,j) = W32(i+28-4j) ----
        {
            const float* b = &bufX[OFF + 4 * tid - 12];
            f32x4 qa = ldv4(b),      qb = ldv4(b + 4),  qc = ldv4(b + 8),  qd = ldv4(b + 12),
                  qe = ldv4(b + 16), qf = ldv4(b + 20), qg = ldv4(b + 24), qh = ldv4(b + 28);
            f32x2 acc[4];
#pragma unroll
            for (int i = 0; i < 4; ++i) { acc[i].x = 0.f; acc[i].y = 0.f; }
#pragma unroll
            for (int j = 0; j < 8; ++j)
#pragma unroll
                for (int i = 0; i < 4; ++i) {
                    float v = W32(i + 28 - 4 * j);
                    f32x2 vv; vv.x = v; vv.y = v;
                    acc[i] = __builtin_elementwise_fma(c[j], vv, acc[i]);
                }
#pragma unroll
            for (int i = 0; i < 4; ++i) { a3[i] = acc[i].x; d3[i] = acc[i].y; }
        }

        // ---- planar staging (pl disjoint from bufX/bufY; pl-readers passed the
        //      post-L2 barrier already, so no extra barrier needed here) ----
        {
            f32x4 v0, v1, v2, v3;
            v0.x=a3[0]; v0.y=a3[1]; v0.z=a3[2]; v0.w=a3[3];
            v1.x=d3[0]; v1.y=d3[1]; v1.z=d3[2]; v1.w=d3[3];
            v2.x=d2[0]; v2.y=d2[1]; v2.z=d2[2]; v2.w=d2[3];
            v3.x=d1[0]; v3.y=d1[1]; v3.z=d1[2]; v3.w=d1[3];
            *reinterpret_cast<f32x4*>(&pl[0][4 * tid]) = v0;
            *reinterpret_cast<f32x4*>(&pl[1][4 * tid]) = v1;
            *reinterpret_cast<f32x4*>(&pl[2][4 * tid]) = v2;
            *reinterpret_cast<f32x4*>(&pl[3][4 * tid]) = v3;
        }
        bar_lds();   // plwrites + L3's bufX reads complete before next stage/store

        xpre = xnext;
        xh = xhn;
    }

    // ---- epilogue: store last segment ----
    {
        f32x4* outr = outb + (NSEGS - 1) * SEG;
#pragma unroll
        for (int k = 0; k < 4; ++k) {
            int t = tid + k * NT;
            f32x4 o;
            o.x = pl[0][t]; o.y = pl[1][t]; o.z = pl[2][t]; o.w = pl[3][t];
            outr[t] = o;
        }
    }
}

extern "C" void kernel_launch(void* const* d_in, const int* in_sizes, int n_in,
                              void* d_out, int out_size, void* d_ws, size_t ws_size,
                              hipStream_t stream) {
    const float* x  = (const float*)d_in[0];
    const float* lo = (const float*)d_in[1];
    const float* hi = (const float*)d_in[2];
    float* out = (float*)d_out;

    const int nblocks = 64 * 32;   // one persistent block per row
    swt_db4_l3_kernel<<<dim3(nblocks), dim3(NT), 0, stream>>>(x, lo, hi, out);
}

// Round 15
// 31.520 us; speedup vs baseline: 1.0273x; 1.0273x over previous
//
#include <hip/hip_runtime.h>

#define TLEN 4096
#define NT 256
#define SEG 1024
#define OFF 24             // left halo capacity (need 21); 96 B -> 16B-aligned
#define BUFW 1088          // 24 + 1024 + 28 = 1076, padded

typedef float f32x4 __attribute__((ext_vector_type(4)));
typedef float f32x2 __attribute__((ext_vector_type(2)));

__device__ __forceinline__ f32x4 ldv4(const float* p) {
    return *reinterpret_cast<const f32x4*>(p);
}

// compile-time window element extraction (all n constant after unroll)
#define W16(n) ((n) < 4 ? qa[(n)] : (n) < 8 ? qb[(n)-4] : (n) < 12 ? qc[(n)-8] : qd[(n)-12])
#define W20(n) ((n) < 4 ? qa[(n)] : (n) < 8 ? qb[(n)-4] : (n) < 12 ? qc[(n)-8] : (n) < 16 ? qd[(n)-12] : qe[(n)-16])
#define W32(n) ((n) < 4 ? qa[(n)] : (n) < 8 ? qb[(n)-4] : (n) < 12 ? qc[(n)-8] : (n) < 16 ? qd[(n)-12] : \
                (n) < 20 ? qe[(n)-16] : (n) < 24 ? qf[(n)-20] : (n) < 28 ? qg[(n)-24] : qh[(n)-28])

__global__ __launch_bounds__(NT) void swt_db4_l3_kernel(
    const float* __restrict__ x,
    const float* __restrict__ lo_g,
    const float* __restrict__ hi_g,
    float* __restrict__ out)
{
    __shared__ float bufX[BUFW];      // x, later A2
    __shared__ float bufY[BUFW];      // A1
    __shared__ float pl[4][SEG];      // channel-planar output staging

    const int bid = blockIdx.x;
    const int row = bid >> 2;
    const int seg = (bid & 3) << 10;  // 0,1024,2048,3072
    const int tid = threadIdx.x;

    // packed (lo, hi) filter pairs; uniform addresses -> scalar regs
    f32x2 c[8];
#pragma unroll
    for (int j = 0; j < 8; ++j) { c[j].x = lo_g[j]; c[j].y = hi_g[j]; }

    const float* xr = x + (size_t)row * TLEN;

    // ---- Stage owned x (dense f32x4) + wrap halo ----
    {
        int idx = 4 * tid;
        *reinterpret_cast<f32x4*>(&bufX[OFF + idx]) = ldv4(xr + seg + idx);
    }
    if (tid < 49) {   // x halo: u in [-21,-1] and [1024,1052)
        int u = (tid < 21) ? (tid - 21) : (SEG + tid - 21);
        bufX[OFF + u] = xr[(seg + u) & (TLEN - 1)];
    }
    __syncthreads();

    float d1[4], d2[4], a3[4], d3[4];

    // ---- Level 1 (dil=1): window [4t-4, 4t+12), tap(i,j) = W16(i+8-j) ----
    {
        const float* b = &bufX[OFF + 4 * tid - 4];
        f32x4 qa = ldv4(b), qb = ldv4(b + 4), qc = ldv4(b + 8), qd = ldv4(b + 12);
        f32x2 acc[4];
#pragma unroll
        for (int i = 0; i < 4; ++i) { acc[i].x = 0.f; acc[i].y = 0.f; }
#pragma unroll
        for (int j = 0; j < 8; ++j)
#pragma unroll
            for (int i = 0; i < 4; ++i) {
                float v = W16(i + 8 - j);
                f32x2 vv; vv.x = v; vv.y = v;
                acc[i] = __builtin_elementwise_fma(c[j], vv, acc[i]);
            }
        f32x4 av; av.x = acc[0].x; av.y = acc[1].x; av.z = acc[2].x; av.w = acc[3].x;
        *reinterpret_cast<f32x4*>(&bufY[OFF + 4 * tid]) = av;
#pragma unroll
        for (int i = 0; i < 4; ++i) d1[i] = acc[i].y;
    }
    if (tid < 42) {   // edge A1 (A only): u in [-18,-1] and [1024,1048)
        int u = (tid < 18) ? (tid - 18) : (SEG + tid - 18);
        const float* s = &bufX[OFF + u];
        float a = 0.f;
#pragma unroll
        for (int j = 0; j < 8; ++j) a = fmaf(c[j].x, s[4 - j], a);
        bufY[OFF + u] = a;
    }
    __syncthreads();

    // ---- Level 2 (dil=2): window [4t-8, 4t+12), tap(i,j) = W20(i+16-2j) ----
    {
        const float* b = &bufY[OFF + 4 * tid - 8];
        f32x4 qa = ldv4(b), qb = ldv4(b + 4), qc = ldv4(b + 8), qd = ldv4(b + 12), qe = ldv4(b + 16);
        f32x2 acc[4];
#pragma unroll
        for (int i = 0; i < 4; ++i) { acc[i].x = 0.f; acc[i].y = 0.f; }
#pragma unroll
        for (int j = 0; j < 8; ++j)
#pragma unroll
            for (int i = 0; i < 4; ++i) {
                float v = W20(i + 16 - 2 * j);
                f32x2 vv; vv.x = v; vv.y = v;
                acc[i] = __builtin_elementwise_fma(c[j], vv, acc[i]);
            }
        f32x4 av; av.x = acc[0].x; av.y = acc[1].x; av.z = acc[2].x; av.w = acc[3].x;
        *reinterpret_cast<f32x4*>(&bufX[OFF + 4 * tid]) = av;   // x dead after L1
#pragma unroll
        for (int i = 0; i < 4; ++i) d2[i] = acc[i].y;
    }
    if (tid < 28) {   // edge A2 (A only): u in [-12,-1] and [1024,1040)
        int u = (tid < 12) ? (tid - 12) : (SEG + tid - 12);
        const float* s = &bufY[OFF + u];
        float a = 0.f;
#pragma unroll
        for (int j = 0; j < 8; ++j) a = fmaf(c[j].x, s[(4 - j) * 2], a);
        bufX[OFF + u] = a;
    }
    __syncthreads();

    // ---- Level 3 (dil=4): window [4t-12, 4t+20), tap(i,j) = W32(i+28-4j) ----
    {
        const float* b = &bufX[OFF + 4 * tid - 12];
        f32x4 qa = ldv4(b),      qb = ldv4(b + 4),  qc = ldv4(b + 8),  qd = ldv4(b + 12),
              qe = ldv4(b + 16), qf = ldv4(b + 20), qg = ldv4(b + 24), qh = ldv4(b + 28);
        f32x2 acc[4];
#pragma unroll
        for (int i = 0; i < 4; ++i) { acc[i].x = 0.f; acc[i].y = 0.f; }
#pragma unroll
        for (int j = 0; j < 8; ++j)
#pragma unroll
            for (int i = 0; i < 4; ++i) {
                float v = W32(i + 28 - 4 * j);
                f32x2 vv; vv.x = v; vv.y = v;
                acc[i] = __builtin_elementwise_fma(c[j], vv, acc[i]);
            }
#pragma unroll
        for (int i = 0; i < 4; ++i) { a3[i] = acc[i].x; d3[i] = acc[i].y; }
    }

    // ---- Planar staging: dense granule-per-lane b128 writes, conflict-free ----
    {
        f32x4 v0, v1, v2, v3;
        v0.x=a3[0]; v0.y=a3[1]; v0.z=a3[2]; v0.w=a3[3];
        v1.x=d3[0]; v1.y=d3[1]; v1.z=d3[2]; v1.w=d3[3];
        v2.x=d2[0]; v2.y=d2[1]; v2.z=d2[2]; v2.w=d2[3];
        v3.x=d1[0]; v3.y=d1[1]; v3.z=d1[2]; v3.w=d1[3];
        *reinterpret_cast<f32x4*>(&pl[0][4 * tid]) = v0;
        *reinterpret_cast<f32x4*>(&pl[1][4 * tid]) = v1;
        *reinterpret_cast<f32x4*>(&pl[2][4 * tid]) = v2;
        *reinterpret_cast<f32x4*>(&pl[3][4 * tid]) = v3;
    }
    __syncthreads();

    // ---- Re-coalesced dense NONTEMPORAL stores: t = tid + 256k, 16-B lane stride ----
    f32x4* outr = reinterpret_cast<f32x4*>(out + (size_t)row * TLEN * 4) + seg;
#pragma unroll
    for (int k = 0; k < 4; ++k) {
        int t = tid + k * NT;
        f32x4 o;
        o.x = pl[0][t];   // A3
        o.y = pl[1][t];   // D3
        o.z = pl[2][t];   // D2
        o.w = pl[3][t];   // D1
        __builtin_nontemporal_store(o, &outr[t]);
    }
}

extern "C" void kernel_launch(void* const* d_in, const int* in_sizes, int n_in,
                              void* d_out, int out_size, void* d_ws, size_t ws_size,
                              hipStream_t stream) {
    const float* x  = (const float*)d_in[0];
    const float* lo = (const float*)d_in[1];
    const float* hi = (const float*)d_in[2];
    float* out = (float*)d_out;

    const int nblocks = 64 * 32 * 4;   // 4 blocks per row
    swt_db4_l3_kernel<<<dim3(nblocks), dim3(NT), 0, stream>>>(x, lo, hi, out);
}